// Round 3
// baseline (585.559 us; speedup 1.0000x reference)
//
#include <hip/hip_runtime.h>
#include <math.h>

#define N_NODES 100000
#define S1 50
#define S2 10
#define HID 128
#define NT 16   // nodes per block in enc2_mlp

// ---------------- kernel 1: agg1d[n] = (sum_{j in neigh1[n]} feat[j] + feat[n]) / 51  (fp64)
// One wave per node; writes 3 doubles (24 B) per node. 2.4 MB total.
__global__ __launch_bounds__(256) void agg1_kernel(
    const float* __restrict__ feat, const int* __restrict__ neigh1,
    double* __restrict__ agg1d)
{
    const int wid  = threadIdx.x >> 6;
    const int lane = threadIdx.x & 63;
    const int n = blockIdx.x * 4 + wid;
    if (n >= N_NODES) return;

    double f0 = 0.0, f1 = 0.0, f2 = 0.0;
    if (lane < S1) {
        int j = neigh1[n * S1 + lane];
        f0 = (double)feat[j * 3 + 0];
        f1 = (double)feat[j * 3 + 1];
        f2 = (double)feat[j * 3 + 2];
    } else if (lane == S1) {
        f0 = (double)feat[n * 3 + 0];
        f1 = (double)feat[n * 3 + 1];
        f2 = (double)feat[n * 3 + 2];
    }
    #pragma unroll
    for (int off = 32; off > 0; off >>= 1) {
        f0 += __shfl_down(f0, off);
        f1 += __shfl_down(f1, off);
        f2 += __shfl_down(f2, off);
    }
    if (lane == 0) {
        agg1d[n * 3 + 0] = f0 / 51.0;
        agg1d[n * 3 + 1] = f1 / 51.0;
        agg1d[n * 3 + 2] = f2 / 51.0;
    }
}

// ---------------- kernel 2: enc2 (recompute h1 rows from agg1d) + MLP + score, all fp64.
// One block = 16 nodes. Weights staged in LDS as FLOAT (exact: they are fp32 inputs),
// row-major with stride 33 (consecutive lanes -> consecutive banks, conflict-free).
// Activations / accumulators are double.
__global__ __launch_bounds__(256) void enc2_mlp_kernel(
    const int* __restrict__ nodes, const int* __restrict__ neigh2,
    const double* __restrict__ agg1d,
    const float* __restrict__ W1, const float* __restrict__ W2,
    const float* __restrict__ w_a, const float* __restrict__ b_a,
    const float* __restrict__ w_b, const float* __restrict__ b_b,
    const float* __restrict__ w_c, const float* __restrict__ b_c,
    const int* __restrict__ psz, const int* __restrict__ npe,
    double* __restrict__ scoresd)
{
    __shared__ float  sW[128 * 33];          // 16.9 KB: one 32-k weight chunk (fp32, exact)
    __shared__ double sA[NT * 128];          // 16 KB  : activations ping (fp64)
    __shared__ double sB[NT * 128];          // 16 KB  : activations pong (fp64)
    __shared__ float  sW1[128 * 3];          // 1.5 KB : W1 (fp32, exact)
    __shared__ double sG[NT * (S2 + 1) * 3]; // 4.2 KB : gathered agg1 rows (fp64)

    const int tid  = threadIdx.x;
    const int base = blockIdx.x * NT;        // 6250*16 == 100000, no guards needed

    // ---- phase 0: stage W1 + gathered agg1 rows (304 items, strided over 256 threads)
    for (int i = tid; i < 128 + NT * (S2 + 1); i += 256) {
        if (i < 128) {
            sW1[i * 3 + 0] = W1[i * 3 + 0];
            sW1[i * 3 + 1] = W1[i * 3 + 1];
            sW1[i * 3 + 2] = W1[i * 3 + 2];
        } else {
            int t  = i - 128;
            int ns = t / 11, j = t - ns * 11;
            int node = nodes[base + ns];
            int src  = (j == 0) ? node : neigh2[node * S2 + (j - 1)];
            sG[t * 3 + 0] = agg1d[src * 3 + 0];
            sG[t * 3 + 1] = agg1d[src * 3 + 1];
            sG[t * 3 + 2] = agg1d[src * 3 + 2];
        }
    }
    __syncthreads();

    // ---- phase 1: agg2[ns][t] = mean_j relu(W1[t] . agg1_row_j)  -> sA   (fp64)
    for (int idx = tid; idx < NT * 128; idx += 256) {
        int ns = idx >> 7, t = idx & 127;
        double wx = (double)sW1[t * 3 + 0];
        double wy = (double)sW1[t * 3 + 1];
        double wz = (double)sW1[t * 3 + 2];
        double acc = 0.0;
        #pragma unroll
        for (int j = 0; j <= S2; j++) {
            const double* a = &sG[(ns * 11 + j) * 3];
            acc += fmax(wx * a[0] + wy * a[1] + wz * a[2], 0.0);
        }
        sA[idx] = acc / 11.0;
    }
    // no barrier needed here: phase-2 staging writes sW only, then barriers before reading sA

    const int tq  = tid & 31;   // output group: outs {tq, tq+32, tq+64, tq+96}
    const int nq  = tid >> 5;   // node group: nodes {2nq, 2nq+1}
    const int ns0 = nq * 2;

    // ---- phase 2: emb = relu(W2 @ agg2) : sA -> sB
    {
        double acc0[4] = {0,0,0,0}, acc1[4] = {0,0,0,0};
        for (int c = 0; c < 4; c++) {
            for (int i = tid; i < 128 * 32; i += 256) {   // stage W2 chunk c (fp32)
                int t = i >> 5, k = i & 31;
                sW[t * 33 + k] = W2[t * 128 + c * 32 + k];
            }
            __syncthreads();
            for (int k = 0; k < 32; k++) {
                double a0 = sA[ns0 * 128 + c * 32 + k];
                double a1 = sA[(ns0 + 1) * 128 + c * 32 + k];
                #pragma unroll
                for (int i = 0; i < 4; i++) {
                    double w = (double)sW[(tq + 32 * i) * 33 + k];
                    acc0[i] += w * a0;
                    acc1[i] += w * a1;
                }
            }
            __syncthreads();
        }
        #pragma unroll
        for (int i = 0; i < 4; i++) {
            sB[ns0 * 128 + tq + 32 * i]       = fmax(acc0[i], 0.0);
            sB[(ns0 + 1) * 128 + tq + 32 * i] = fmax(acc1[i], 0.0);
        }
    }

    // ---- phase 3: xa = relu(w_a[:, :128] @ emb + w_a[:,128]*rem + b_a) : sB -> sA
    {
        double acc0[4] = {0,0,0,0}, acc1[4] = {0,0,0,0};
        for (int c = 0; c < 4; c++) {
            for (int i = tid; i < 128 * 32; i += 256) {   // stage w_a chunk c (cols 0..127)
                int o = i >> 5, k = i & 31;
                sW[o * 33 + k] = w_a[o * 129 + c * 32 + k];
            }
            __syncthreads();
            for (int k = 0; k < 32; k++) {
                double a0 = sB[ns0 * 128 + c * 32 + k];
                double a1 = sB[(ns0 + 1) * 128 + c * 32 + k];
                #pragma unroll
                for (int i = 0; i < 4; i++) {
                    double w = (double)sW[(tq + 32 * i) * 33 + k];
                    acc0[i] += w * a0;
                    acc1[i] += w * a1;
                }
            }
            __syncthreads();
        }
        const double rem = (double)(psz[0] - npe[0]);
        #pragma unroll
        for (int i = 0; i < 4; i++) {
            int o = tq + 32 * i;
            double add = (double)w_a[o * 129 + 128] * rem + (double)b_a[o];
            sA[ns0 * 128 + o]       = fmax(acc0[i] + add, 0.0);
            sA[(ns0 + 1) * 128 + o] = fmax(acc1[i] + add, 0.0);
        }
    }

    // ---- phase 4: xb = relu(w_b @ xa + b_b) : sA -> sB[ns*64 + o], o < 64
    {
        double acc0[2] = {0,0}, acc1[2] = {0,0};
        for (int c = 0; c < 4; c++) {
            for (int i = tid; i < 64 * 32; i += 256) {    // stage w_b chunk c
                int o = i >> 5, k = i & 31;
                sW[o * 33 + k] = w_b[o * 128 + c * 32 + k];
            }
            __syncthreads();
            for (int k = 0; k < 32; k++) {
                double a0 = sA[ns0 * 128 + c * 32 + k];
                double a1 = sA[(ns0 + 1) * 128 + c * 32 + k];
                #pragma unroll
                for (int i = 0; i < 2; i++) {
                    double w = (double)sW[(tq + 32 * i) * 33 + k];
                    acc0[i] += w * a0;
                    acc1[i] += w * a1;
                }
            }
            __syncthreads();
        }
        #pragma unroll
        for (int i = 0; i < 2; i++) {
            int o = tq + 32 * i;
            double bb = (double)b_b[o];
            sB[ns0 * 64 + o]       = fmax(acc0[i] + bb, 0.0);
            sB[(ns0 + 1) * 64 + o] = fmax(acc1[i] + bb, 0.0);
        }
    }
    __syncthreads();

    // ---- phase 5: score = w_c . xb + b_c   (16 threads per node)
    {
        const int j = tid & 15, ns = tid >> 4;
        double v = 0.0;
        #pragma unroll
        for (int r = 0; r < 4; r++)
            v += (double)w_c[j + 16 * r] * sB[ns * 64 + j + 16 * r];
        v += __shfl_down(v, 8);
        v += __shfl_down(v, 4);
        v += __shfl_down(v, 2);
        v += __shfl_down(v, 1);
        if (j == 0)
            scoresd[base + ns] = v + (double)b_c[0];
    }
}

// ---------------- softmax chain (fp64, final store fp32) ----------------
__global__ __launch_bounds__(256) void reduce_max_kernel(
    const double* __restrict__ s, double* __restrict__ pmax)
{
    __shared__ double red[4];
    const int tid = threadIdx.x;
    double m = -INFINITY;
    for (int i = blockIdx.x * 256 + tid; i < N_NODES; i += gridDim.x * 256)
        m = fmax(m, s[i]);
    #pragma unroll
    for (int off = 32; off > 0; off >>= 1) m = fmax(m, __shfl_down(m, off));
    if ((tid & 63) == 0) red[tid >> 6] = m;
    __syncthreads();
    if (tid == 0)
        pmax[blockIdx.x] = fmax(fmax(red[0], red[1]), fmax(red[2], red[3]));
}

__global__ __launch_bounds__(256) void final_max_kernel(
    const double* __restrict__ pmax, double* __restrict__ M, int nb)
{
    __shared__ double red[4];
    const int tid = threadIdx.x;
    double m = -INFINITY;
    for (int i = tid; i < nb; i += 256) m = fmax(m, pmax[i]);
    #pragma unroll
    for (int off = 32; off > 0; off >>= 1) m = fmax(m, __shfl_down(m, off));
    if ((tid & 63) == 0) red[tid >> 6] = m;
    __syncthreads();
    if (tid == 0)
        M[0] = fmax(fmax(red[0], red[1]), fmax(red[2], red[3]));
}

__global__ __launch_bounds__(256) void exp_kernel(
    double* __restrict__ s, const double* __restrict__ M,
    double* __restrict__ psum)
{
    __shared__ double red[4];
    const int tid = threadIdx.x;
    const double m = M[0];
    double acc = 0.0;
    for (int i = blockIdx.x * 256 + tid; i < N_NODES; i += gridDim.x * 256) {
        double e = exp(s[i] - m);
        s[i] = e;
        acc += e;
    }
    #pragma unroll
    for (int off = 32; off > 0; off >>= 1) acc += __shfl_down(acc, off);
    if ((tid & 63) == 0) red[tid >> 6] = acc;
    __syncthreads();
    if (tid == 0)
        psum[blockIdx.x] = (red[0] + red[1]) + (red[2] + red[3]);
}

__global__ __launch_bounds__(256) void final_sum_kernel(
    const double* __restrict__ psum, double* __restrict__ invS, int nb)
{
    __shared__ double red[4];
    const int tid = threadIdx.x;
    double acc = 0.0;
    for (int i = tid; i < nb; i += 256) acc += psum[i];
    #pragma unroll
    for (int off = 32; off > 0; off >>= 1) acc += __shfl_down(acc, off);
    if ((tid & 63) == 0) red[tid >> 6] = acc;
    __syncthreads();
    if (tid == 0)
        invS[0] = 1.0 / ((red[0] + red[1]) + (red[2] + red[3]));
}

__global__ __launch_bounds__(256) void scale_kernel(
    const double* __restrict__ e, const double* __restrict__ invS,
    float* __restrict__ out)
{
    const double s = invS[0];
    const int i = blockIdx.x * 256 + threadIdx.x;
    if (i < N_NODES) out[i] = (float)(e[i] * s);
}

// ---------------- launch ----------------
extern "C" void kernel_launch(void* const* d_in, const int* in_sizes, int n_in,
                              void* d_out, int out_size, void* d_ws, size_t ws_size,
                              hipStream_t stream)
{
    const int*   nodes = (const int*)  d_in[0];
    const float* feat  = (const float*)d_in[1];
    const int*   n1    = (const int*)  d_in[2];
    const int*   n2    = (const int*)  d_in[3];
    const float* W1    = (const float*)d_in[4];
    const float* W2    = (const float*)d_in[5];
    const float* w_a   = (const float*)d_in[6];
    const float* b_a   = (const float*)d_in[7];
    const float* w_b   = (const float*)d_in[8];
    const float* b_b   = (const float*)d_in[9];
    const float* w_c   = (const float*)d_in[10];
    const float* b_c   = (const float*)d_in[11];
    const int*   psz   = (const int*)  d_in[12];
    const int*   npe   = (const int*)  d_in[13];
    float* out = (float*)d_out;

    // workspace: agg1d (2.4 MB) + scoresd (0.8 MB) + partials (~4 KB)
    double* agg1d   = (double*)d_ws;
    double* scoresd = agg1d + (size_t)N_NODES * 3;
    double* pmax    = scoresd + N_NODES;   // 256
    double* psum    = pmax + 256;          // 256
    double* Mv      = psum + 256;          // 1
    double* invS    = Mv + 1;              // 1

    agg1_kernel<<<(N_NODES + 3) / 4, 256, 0, stream>>>(feat, n1, agg1d);
    enc2_mlp_kernel<<<N_NODES / NT, 256, 0, stream>>>(
        nodes, n2, agg1d, W1, W2, w_a, b_a, w_b, b_b, w_c, b_c, psz, npe, scoresd);
    reduce_max_kernel<<<256, 256, 0, stream>>>(scoresd, pmax);
    final_max_kernel<<<1, 256, 0, stream>>>(pmax, Mv, 256);
    exp_kernel<<<256, 256, 0, stream>>>(scoresd, Mv, psum);
    final_sum_kernel<<<1, 256, 0, stream>>>(psum, invS, 256);
    scale_kernel<<<(N_NODES + 255) / 256, 256, 0, stream>>>(scoresd, invS, out);
}